// Round 3
// baseline (151.335 us; speedup 1.0000x reference)
//
#include <hip/hip_runtime.h>
#include <hip/hip_bf16.h>

typedef __attribute__((ext_vector_type(8))) short short8;
typedef __attribute__((ext_vector_type(4))) float float4v;

#define N_ROWS 4096
#define K_DIM  192
#define TILE   128
#define NT     32          // 4096/128 tiles per dim
#define NSYM   528         // 32*33/2 upper-triangular blocks
#define NBLK   2080        // 2*528 + 1024
#define C1     (-0.72134752044448179f)   // -0.5*log2(e)
#define LOG2E  (1.4426950408889634f)

// ---- kernel 1: fp32 -> bf16 convert + per-row sum of squares (of bf16 values) ----
__global__ void prep_kernel(const float* __restrict__ x, const float* __restrict__ y,
                            __hip_bfloat16* __restrict__ xb, __hip_bfloat16* __restrict__ yb,
                            float* __restrict__ sqx, float* __restrict__ sqy,
                            unsigned* __restrict__ ctrl /* 3 float sums + 1 counter */)
{
    if (blockIdx.x == 0 && threadIdx.x < 4) ctrl[threadIdx.x] = 0u;  // zero sums + counter
    int w    = (blockIdx.x * blockDim.x + threadIdx.x) >> 6;  // one row per wave
    int lane = threadIdx.x & 63;
    if (w >= 2 * N_ROWS) return;
    const float*      src = (w < N_ROWS) ? (x + (size_t)w * K_DIM) : (y + (size_t)(w - N_ROWS) * K_DIM);
    __hip_bfloat16*   dst = (w < N_ROWS) ? (xb + (size_t)w * K_DIM) : (yb + (size_t)(w - N_ROWS) * K_DIM);
    float s = 0.f;
    #pragma unroll
    for (int i = 0; i < 3; ++i) {                // 192 = 3 * 64
        float f = src[lane + 64 * i];
        __hip_bfloat16 h = __float2bfloat16(f);
        dst[lane + 64 * i] = h;
        float fb = __bfloat162float(h);
        s += fb * fb;
    }
    #pragma unroll
    for (int off = 32; off; off >>= 1) s += __shfl_down(s, off, 64);
    if (lane == 0) {
        if (w < N_ROWS) sqx[w] = s; else sqy[w - N_ROWS] = s;
    }
}

// ---- kernel 2: fused Gram + exp + reduce + (last block) final loss ----
// block = 256 threads = 4 independent waves, each computing a 64x64 quadrant
// of a 128x128 tile. NO LDS staging: MFMA fragments are loaded directly from
// global (L2-resident) — the fragment pattern (16 rows x 64B) is fully
// 64B-coalesced. No barriers in the main loop -> waves run independently.
__global__ __launch_bounds__(256, 3)
void gram_kernel(const __hip_bfloat16* __restrict__ xb, const __hip_bfloat16* __restrict__ yb,
                 const float* __restrict__ sqx, const float* __restrict__ sqy,
                 float* __restrict__ sums, unsigned* __restrict__ counter,
                 const float* __restrict__ avg_step, float* __restrict__ out)
{
    __shared__ float wred[4];

    const short* xbs = (const short*)xb;
    const short* ybs = (const short*)yb;

    int id = blockIdx.x;
    const short *A, *B; const float *sa, *sb;
    int bi, bj, cls;
    float weight = 1.0f;
    if (id < 2 * NSYM) {
        int t;
        if (id < NSYM) { t = id;        A = xbs; B = xbs; sa = sqx; sb = sqx; cls = 0; }
        else           { t = id - NSYM; A = ybs; B = ybs; sa = sqy; sb = sqy; cls = 1; }
        bi = 0;
        while (t >= NT - bi) { t -= NT - bi; ++bi; }   // unrank upper triangle
        bj = bi + t;
        if (bi != bj) weight = 2.0f;                   // symmetry: off-diagonal counts twice
    } else {
        int t = id - 2 * NSYM;
        bi = t >> 5; bj = t & 31;
        A = xbs; B = ybs; sa = sqx; sb = sqy; cls = 2;
    }
    const int abase = bi * TILE, bbase = bj * TILE;

    const int tid  = threadIdx.x;
    const int lane = tid & 63, w = tid >> 6;
    const int wm   = w >> 1,  wn = w & 1;
    const int m15  = lane & 15, quad = lane >> 4;

    // per-lane fragment base pointers (row = base + tm*16 + m15, k-chunk = quad*8)
    const short* Ab = A + (size_t)(abase + wm * 64 + m15) * K_DIM + quad * 8;
    const short* Bb = B + (size_t)(bbase + wn * 64 + m15) * K_DIM + quad * 8;
    const short* Ap[4]; const short* Bp[4];
    #pragma unroll
    for (int tm = 0; tm < 4; ++tm) {
        Ap[tm] = Ab + tm * 16 * K_DIM;
        Bp[tm] = Bb + tm * 16 * K_DIM;
    }

    // sq terms (scaled by C1)
    float4v ua[4]; float vb4[4];
    #pragma unroll
    for (int tm = 0; tm < 4; ++tm)
        ua[tm] = (*(const float4v*)&sa[abase + wm * 64 + tm * 16 + quad * 4]) * C1;
    #pragma unroll
    for (int tn = 0; tn < 4; ++tn)
        vb4[tn] = C1 * sb[bbase + wn * 64 + tn * 16 + m15];

    float4v acc[4][4];
    #pragma unroll
    for (int i = 0; i < 4; ++i)
        #pragma unroll
        for (int j = 0; j < 4; ++j) acc[i][j] = (float4v){0.f, 0.f, 0.f, 0.f};

    // K = 192 = 6 chunks of 32; fragments straight from global (L2-resident)
    #pragma unroll
    for (int ks = 0; ks < 6; ++ks) {
        short8 af[4], bfr[4];
        #pragma unroll
        for (int tm = 0; tm < 4; ++tm) af[tm]  = *(const short8*)(Ap[tm] + ks * 32);
        #pragma unroll
        for (int tn = 0; tn < 4; ++tn) bfr[tn] = *(const short8*)(Bp[tn] + ks * 32);
        #pragma unroll
        for (int tm = 0; tm < 4; ++tm)
            #pragma unroll
            for (int tn = 0; tn < 4; ++tn)
                acc[tm][tn] = __builtin_amdgcn_mfma_f32_16x16x32_bf16(af[tm], bfr[tn], acc[tm][tn], 0, 0, 0);
    }

    // epilogue: sum exp2(min(C1*sqa + C1*sqb + log2e*g, 0)), skipping underflowing tiles
    float lsum = 0.f;
    #pragma unroll
    for (int tm = 0; tm < 4; ++tm)
        #pragma unroll
        for (int tn = 0; tn < 4; ++tn) {
            float vv = vb4[tn];
            float s0 = fminf(ua[tm][0] + vv + LOG2E * acc[tm][tn][0], 0.f);
            float s1 = fminf(ua[tm][1] + vv + LOG2E * acc[tm][tn][1], 0.f);
            float s2 = fminf(ua[tm][2] + vv + LOG2E * acc[tm][tn][2], 0.f);
            float s3 = fminf(ua[tm][3] + vv + LOG2E * acc[tm][tn][3], 0.f);
            float mx = fmaxf(fmaxf(s0, s1), fmaxf(s2, s3));
            if (__ballot(mx > -40.f)) {   // whole 16x16 tile underflows -> skip (execz)
                lsum += __builtin_amdgcn_exp2f(s0) + __builtin_amdgcn_exp2f(s1)
                      + __builtin_amdgcn_exp2f(s2) + __builtin_amdgcn_exp2f(s3);
            }
        }

    #pragma unroll
    for (int off = 32; off; off >>= 1) lsum += __shfl_down(lsum, off, 64);
    if (lane == 0) wred[w] = lsum;
    __syncthreads();
    if (tid == 0) {
        float p = weight * (wred[0] + wred[1] + wred[2] + wred[3]);
        atomicAdd(&sums[cls], p);
        __threadfence();
        unsigned done = atomicAdd(counter, 1u);
        if (done == NBLK - 1) {            // last block finalizes
            __threadfence();
            float sxx = atomicAdd(&sums[0], 0.0f);
            float syy = atomicAdd(&sums[1], 0.0f);
            float sxy = atomicAdd(&sums[2], 0.0f);
            const float inv = 1.0f / 16777216.0f;   // 1/4096^2
            float mmd   = (sxx + syy - 2.0f * sxy) * inv;
            float stepv = fmaxf(1.0f, avg_step[0]);
            out[0] = mmd + (stepv - 1.0f) * 0.002f;
            out[1] = mmd;
        }
    }
}

extern "C" void kernel_launch(void* const* d_in, const int* in_sizes, int n_in,
                              void* d_out, int out_size, void* d_ws, size_t ws_size,
                              hipStream_t stream)
{
    const float* x        = (const float*)d_in[0];
    const float* y        = (const float*)d_in[1];
    const float* avg_step = (const float*)d_in[2];

    char* ws = (char*)d_ws;
    // ws layout: xb | yb | sqx | sqy | sums(3 f32) + counter(1 u32)
    __hip_bfloat16* xb      = (__hip_bfloat16*)(ws);
    __hip_bfloat16* yb      = (__hip_bfloat16*)(ws + 1572864);
    float*          sqx     = (float*)(ws + 3145728);
    float*          sqy     = (float*)(ws + 3162112);
    float*          sums    = (float*)(ws + 3178496);
    unsigned*       counter = (unsigned*)(ws + 3178508);

    prep_kernel<<<2048, 256, 0, stream>>>(x, y, xb, yb, sqx, sqy, (unsigned*)sums);
    gram_kernel<<<NBLK, 256, 0, stream>>>(xb, yb, sqx, sqy, sums, counter,
                                          avg_step, (float*)d_out);
}

// Round 4
// 96.332 us; speedup vs baseline: 1.5710x; 1.5710x over previous
//
#include <hip/hip_runtime.h>
#include <hip/hip_bf16.h>

typedef __attribute__((ext_vector_type(8))) short short8;
typedef __attribute__((ext_vector_type(4))) float float4v;

#define N_ROWS 4096
#define K_DIM  192
#define NT     32                       // 128-row tiles per dim
#define NXX    272                      // paired upper-tri blocks per symmetric matrix
#define NBLK   1056                     // 272 + 272 + 512
#define STRE   104                      // LDS row stride in elems per stage (96 + 8 pad)
#define STAGE_BYTES (384 * STRE * 2)    // 79,872 B per K-stage (128 A rows + 256 B rows)
#define LDS_TOTAL   (2 * STAGE_BYTES + 32)
#define C1     (-0.72134752044448179f)  // -0.5*log2(e)
#define LOG2E  (1.4426950408889634f)

// ---- kernel 1: fp32 -> bf16 convert + per-row sum of squares (of bf16 values) ----
__global__ void prep_kernel(const float* __restrict__ x, const float* __restrict__ y,
                            __hip_bfloat16* __restrict__ xb, __hip_bfloat16* __restrict__ yb,
                            float* __restrict__ sqx, float* __restrict__ sqy)
{
    int w    = (blockIdx.x * blockDim.x + threadIdx.x) >> 6;  // one row per wave
    int lane = threadIdx.x & 63;
    if (w >= 2 * N_ROWS) return;
    const float*      src = (w < N_ROWS) ? (x + (size_t)w * K_DIM) : (y + (size_t)(w - N_ROWS) * K_DIM);
    __hip_bfloat16*   dst = (w < N_ROWS) ? (xb + (size_t)w * K_DIM) : (yb + (size_t)(w - N_ROWS) * K_DIM);
    float s = 0.f;
    #pragma unroll
    for (int i = 0; i < 3; ++i) {                // 192 = 3 * 64
        float f = src[lane + 64 * i];
        __hip_bfloat16 h = __float2bfloat16(f);
        dst[lane + 64 * i] = h;
        float fb = __bfloat162float(h);
        s += fb * fb;
    }
    #pragma unroll
    for (int off = 32; off; off >>= 1) s += __shfl_down(s, off, 64);
    if (lane == 0) {
        if (w < N_ROWS) sqx[w] = s; else sqy[w - N_ROWS] = s;
    }
}

// ---- kernel 2: fused Gram + exp + block reduce ----
// 512 threads = 8 waves; tile = 128 rows x 256 cols; wave (wm,wn) owns a 64x64
// quadrant. Full K=192 staged as TWO独立 LDS regions of 96 -> stage-1 global
// loads issue after barrier-1 and hide under stage-0 compute; barrier-2 has no
// outstanding global traffic to drain.
extern __shared__ char smem[];

__global__ __launch_bounds__(512, 2)
void gram_kernel(const __hip_bfloat16* __restrict__ xb, const __hip_bfloat16* __restrict__ yb,
                 const float* __restrict__ sqx, const float* __restrict__ sqy,
                 float* __restrict__ partials)
{
    const short* xbs = (const short*)xb;
    const short* ybs = (const short*)yb;

    int id = blockIdx.x;
    const short *A, *B; const float *sa, *sb;
    int bi, bj0, ntiles, sym;
    if (id < 2 * NXX) {
        int t;
        if (id < NXX) { t = id;       A = xbs; B = xbs; sa = sqx; sb = sqx; }
        else          { t = id - NXX; A = ybs; B = ybs; sa = sqy; sb = sqy; }
        bi = 0;
        for (;;) { int nb = (33 - bi) >> 1; if (t < nb) break; t -= nb; ++bi; }
        bj0 = bi + 2 * t;                        // first 128-col subtile
        ntiles = (bj0 + 1 < NT) ? 2 : 1;
        sym = 1;
    } else {
        int t = id - 2 * NXX;
        bi = t >> 4; bj0 = (t & 15) * 2; ntiles = 2;
        A = xbs; B = ybs; sa = sqx; sb = sqy; sym = 0;
    }
    const int abase = bi * 128, bbase = bj0 * 128;

    const int tid  = threadIdx.x;
    const int lane = tid & 63, w = tid >> 6;     // w 0..7
    const int wm   = w >> 2,  wn = w & 3;        // wm: 64-row half, wn: 64-col quarter
    const int m15  = lane & 15, quad = lane >> 4;

    // ---- staging: 9 x 16B chunks per thread per stage (384 rows x 192B) ----
    const short* gsrc[9];
    int ldst[9];
    #pragma unroll
    for (int i = 0; i < 9; ++i) {
        int c   = tid + 512 * i;                 // 0..4607
        int row = (c * 10923) >> 17;             // c / 12 (exact in range)
        int cw  = c - row * 12;
        const short* P; int gr;
        if (row < 128) { P = A; gr = abase + row; }
        else           { P = B; gr = bbase + row - 128; if (gr > N_ROWS - 1) gr = N_ROWS - 1; }
        gsrc[i] = P + (size_t)gr * K_DIM + cw * 8;
        ldst[i] = row * (STRE * 2) + cw * 16;
    }

    // issue stage-0 loads immediately
    uint4 v0[9];
    #pragma unroll
    for (int i = 0; i < 9; ++i) v0[i] = *(const uint4*)(gsrc[i]);

    // sq terms (scaled by C1); clamp col index for the 3% half-empty blocks
    float4v ua[4]; float vb4[4];
    #pragma unroll
    for (int tm = 0; tm < 4; ++tm)
        ua[tm] = (*(const float4v*)&sa[abase + wm * 64 + tm * 16 + quad * 4]) * C1;
    #pragma unroll
    for (int tn = 0; tn < 4; ++tn) {
        int ci = bbase + wn * 64 + tn * 16 + m15;
        if (ci > N_ROWS - 1) ci = N_ROWS - 1;
        vb4[tn] = C1 * sb[ci];
    }

    float weight = 1.0f;
    if (sym) {
        int sub = wn >> 1;                       // which 128-col subtile this wave is in
        weight = (sub >= ntiles) ? 0.0f : (((bj0 + sub) == bi) ? 1.0f : 2.0f);
    }

    // write stage-0 to LDS region 0, barrier
    #pragma unroll
    for (int i = 0; i < 9; ++i) *(uint4*)(smem + ldst[i]) = v0[i];
    __syncthreads();

    // issue stage-1 loads NOW — latency hides under stage-0 compute
    uint4 v1[9];
    #pragma unroll
    for (int i = 0; i < 9; ++i) v1[i] = *(const uint4*)(gsrc[i] + 96);

    // fragment LDS offsets within a stage region
    int offA[4], offB[4];
    #pragma unroll
    for (int tm = 0; tm < 4; ++tm)
        offA[tm] = (wm * 64 + tm * 16 + m15) * (STRE * 2) + quad * 16;
    #pragma unroll
    for (int tn = 0; tn < 4; ++tn)
        offB[tn] = (128 + wn * 64 + tn * 16 + m15) * (STRE * 2) + quad * 16;

    float4v acc[4][4];
    #pragma unroll
    for (int i = 0; i < 4; ++i)
        #pragma unroll
        for (int j = 0; j < 4; ++j) acc[i][j] = (float4v){0.f, 0.f, 0.f, 0.f};

    // ---- stage-0 compute (LDS region 0) ----
    #pragma unroll
    for (int ks = 0; ks < 3; ++ks) {
        short8 af[4], bfr[4];
        #pragma unroll
        for (int tm = 0; tm < 4; ++tm) af[tm]  = *(const short8*)(smem + offA[tm] + ks * 64);
        #pragma unroll
        for (int tn = 0; tn < 4; ++tn) bfr[tn] = *(const short8*)(smem + offB[tn] + ks * 64);
        #pragma unroll
        for (int tm = 0; tm < 4; ++tm)
            #pragma unroll
            for (int tn = 0; tn < 4; ++tn)
                acc[tm][tn] = __builtin_amdgcn_mfma_f32_16x16x32_bf16(af[tm], bfr[tn], acc[tm][tn], 0, 0, 0);
    }

    // write stage-1 to region 1 (distinct memory — no hazard with ongoing reads)
    #pragma unroll
    for (int i = 0; i < 9; ++i) *(uint4*)(smem + STAGE_BYTES + ldst[i]) = v1[i];
    __syncthreads();

    // ---- stage-1 compute (LDS region 1) ----
    #pragma unroll
    for (int ks = 0; ks < 3; ++ks) {
        short8 af[4], bfr[4];
        #pragma unroll
        for (int tm = 0; tm < 4; ++tm) af[tm]  = *(const short8*)(smem + STAGE_BYTES + offA[tm] + ks * 64);
        #pragma unroll
        for (int tn = 0; tn < 4; ++tn) bfr[tn] = *(const short8*)(smem + STAGE_BYTES + offB[tn] + ks * 64);
        #pragma unroll
        for (int tm = 0; tm < 4; ++tm)
            #pragma unroll
            for (int tn = 0; tn < 4; ++tn)
                acc[tm][tn] = __builtin_amdgcn_mfma_f32_16x16x32_bf16(af[tm], bfr[tn], acc[tm][tn], 0, 0, 0);
    }

    // ---- epilogue: sum exp2(min(C1*sqa + C1*sqb + log2e*g, 0)), skip underflow tiles ----
    float lsum = 0.f;
    #pragma unroll
    for (int tm = 0; tm < 4; ++tm)
        #pragma unroll
        for (int tn = 0; tn < 4; ++tn) {
            float vv = vb4[tn];
            float s0 = fminf(ua[tm][0] + vv + LOG2E * acc[tm][tn][0], 0.f);
            float s1 = fminf(ua[tm][1] + vv + LOG2E * acc[tm][tn][1], 0.f);
            float s2 = fminf(ua[tm][2] + vv + LOG2E * acc[tm][tn][2], 0.f);
            float s3 = fminf(ua[tm][3] + vv + LOG2E * acc[tm][tn][3], 0.f);
            float mx = fmaxf(fmaxf(s0, s1), fmaxf(s2, s3));
            if (__ballot(mx > -40.f)) {
                lsum += __builtin_amdgcn_exp2f(s0) + __builtin_amdgcn_exp2f(s1)
                      + __builtin_amdgcn_exp2f(s2) + __builtin_amdgcn_exp2f(s3);
            }
        }

    #pragma unroll
    for (int off = 32; off; off >>= 1) lsum += __shfl_down(lsum, off, 64);
    float* wred = (float*)(smem + 2 * STAGE_BYTES);
    if (lane == 0) wred[w] = weight * lsum;
    __syncthreads();
    if (tid == 0) {
        float p = 0.f;
        #pragma unroll
        for (int i = 0; i < 8; ++i) p += wred[i];
        partials[id] = p;
    }
}

// ---- kernel 3: final reduce + loss ----
__global__ void final_kernel(const float* __restrict__ partials, const float* __restrict__ avg_step,
                             float* __restrict__ out)
{
    __shared__ float red[3][4];
    int tid = threadIdx.x, lane = tid & 63, w = tid >> 6;
    float s0 = 0.f, s1 = 0.f, s2 = 0.f;
    for (int i = tid; i < NXX; i += 256) s0 += partials[i];
    for (int i = tid; i < NXX; i += 256) s1 += partials[NXX + i];
    for (int i = tid; i < 512; i += 256) s2 += partials[2 * NXX + i];
    #pragma unroll
    for (int off = 32; off; off >>= 1) {
        s0 += __shfl_down(s0, off, 64);
        s1 += __shfl_down(s1, off, 64);
        s2 += __shfl_down(s2, off, 64);
    }
    if (lane == 0) { red[0][w] = s0; red[1][w] = s1; red[2][w] = s2; }
    __syncthreads();
    if (tid == 0) {
        float sxx = red[0][0] + red[0][1] + red[0][2] + red[0][3];
        float syy = red[1][0] + red[1][1] + red[1][2] + red[1][3];
        float sxy = red[2][0] + red[2][1] + red[2][2] + red[2][3];
        const float inv = 1.0f / 16777216.0f;   // 1/4096^2
        float mmd   = (sxx + syy - 2.0f * sxy) * inv;
        float stepv = fmaxf(1.0f, avg_step[0]);
        out[0] = mmd + (stepv - 1.0f) * 0.002f;
        out[1] = mmd;
    }
}

extern "C" void kernel_launch(void* const* d_in, const int* in_sizes, int n_in,
                              void* d_out, int out_size, void* d_ws, size_t ws_size,
                              hipStream_t stream)
{
    const float* x        = (const float*)d_in[0];
    const float* y        = (const float*)d_in[1];
    const float* avg_step = (const float*)d_in[2];

    char* ws = (char*)d_ws;
    __hip_bfloat16* xb       = (__hip_bfloat16*)(ws);
    __hip_bfloat16* yb       = (__hip_bfloat16*)(ws + 1572864);
    float*          sqx      = (float*)(ws + 3145728);
    float*          sqy      = (float*)(ws + 3162112);
    float*          partials = (float*)(ws + 3178496);

    hipFuncSetAttribute(reinterpret_cast<const void*>(gram_kernel),
                        hipFuncAttributeMaxDynamicSharedMemorySize, LDS_TOTAL);

    prep_kernel<<<2048, 256, 0, stream>>>(x, y, xb, yb, sqx, sqy);
    gram_kernel<<<NBLK, 512, LDS_TOTAL, stream>>>(xb, yb, sqx, sqy, partials);
    final_kernel<<<1, 256, 0, stream>>>(partials, avg_step, (float*)d_out);
}